// Round 1
// baseline (2178.789 us; speedup 1.0000x reference)
//
#include <hip/hip_runtime.h>
#include <stdint.h>

typedef __attribute__((ext_vector_type(8))) short short8;
typedef __attribute__((ext_vector_type(4))) float floatx4;

#define NB 2048
#define TT 128
#define DD 128

__device__ __forceinline__ short f2bf(float f) {
  union { float f; uint32_t u; } v; v.f = f;
  uint32_t u = v.u;
  u += 0x7fffu + ((u >> 16) & 1u);   // round-to-nearest-even
  return (short)(u >> 16);
}

__device__ __forceinline__ float sigf(float x) {
  return __builtin_amdgcn_rcpf(1.f + __expf(-x));
}
__device__ __forceinline__ float tanhf_(float x) {
  return 2.f * __builtin_amdgcn_rcpf(1.f + __expf(-2.f * x)) - 1.f;
}

// src: fp32 [K][256] row-major (Keras kernel layout), dst: bf16 [256][K]
__global__ void wtrans(const float* __restrict__ src, short* __restrict__ dst, int K) {
  int n = blockIdx.x;   // 0..255 gate column
  int k = threadIdx.x;  // 0..K-1
  dst[n * K + k] = f2bf(src[k * 256 + n]);
}

// One wave (64 threads) per 16 batch rows. Entire T-loop inside, both layers fused.
// MFMA 16x16x32 bf16 layouts (verified m89/m120):
//   A-frag: A[m = lane&15][k = (lane>>4)*8 + j]   (j = 0..7, +32 per kstep)
//   B-frag: B[k = (lane>>4)*8 + j][n = lane&15]
//   C/D   : col = lane&15, row = (lane>>4)*4 + reg
__global__ __launch_bounds__(64, 1) void lstm_fused(
    const float* __restrict__ x,
    const short* __restrict__ w1t, const short* __restrict__ u1t,
    const short* __restrict__ w2t, const short* __restrict__ u2t,
    const float* __restrict__ b1, const float* __restrict__ b2,
    float* __restrict__ out) {
  __shared__ short hbuf[16 * 64];  // h staging, XOR-swizzled 16B groups

  const int lane = threadIdx.x;
  const int mrow = lane & 15;
  const int quad = lane >> 4;
  const int rowbase = blockIdx.x * 16;

  float bias1[16], bias2[16];
#pragma unroll
  for (int n = 0; n < 16; ++n) {
    bias1[n] = b1[n * 16 + mrow];
    bias2[n] = b2[n * 16 + mrow];
  }

  const float* xp = x + (size_t)(rowbase + mrow) * (TT * DD) + quad * 8;
  const short* w1p = w1t + mrow * 128 + quad * 8;
  const short* u1p = u1t + mrow * 64 + quad * 8;
  const short* w2p = w2t + mrow * 64 + quad * 8;
  const short* u2p = u2t + mrow * 64 + quad * 8;
  float* outp = out + (size_t)rowbase * 8192;

  short8 h1f[2], h2f[2];
  floatx4 c1[4], c2[4];
#pragma unroll
  for (int s = 0; s < 2; ++s)
#pragma unroll
    for (int j = 0; j < 8; ++j) { h1f[s][j] = 0; h2f[s][j] = 0; }
#pragma unroll
  for (int q = 0; q < 4; ++q)
#pragma unroll
    for (int r = 0; r < 4; ++r) { c1[q][r] = 0.f; c2[q][r] = 0.f; }

#pragma unroll 1
  for (int t = 0; t < TT; ++t) {
    // ---- layer 1: z1 = b1 + x_t @ W1 + h1 @ U1 ----
    floatx4 acc[16];
#pragma unroll
    for (int n = 0; n < 16; ++n) acc[n] = floatx4{bias1[n], bias1[n], bias1[n], bias1[n]};

    short8 xf[4];
    const float* xt = xp + t * DD;
#pragma unroll
    for (int s = 0; s < 4; ++s) {
      floatx4 a0 = *(const floatx4*)(xt + s * 32);
      floatx4 a1 = *(const floatx4*)(xt + s * 32 + 4);
      short8 v;
#pragma unroll
      for (int j = 0; j < 4; ++j) { v[j] = f2bf(a0[j]); v[4 + j] = f2bf(a1[j]); }
      xf[s] = v;
    }

#pragma unroll
    for (int n = 0; n < 16; ++n) {
#pragma unroll
      for (int s = 0; s < 4; ++s)
        acc[n] = __builtin_amdgcn_mfma_f32_16x16x32_bf16(
            xf[s], *(const short8*)(w1p + n * 2048 + s * 32), acc[n], 0, 0, 0);
#pragma unroll
      for (int s = 0; s < 2; ++s)
        acc[n] = __builtin_amdgcn_mfma_f32_16x16x32_bf16(
            h1f[s], *(const short8*)(u1p + n * 1024 + s * 32), acc[n], 0, 0, 0);
    }

    // ---- layer 1 elementwise (gate tiles: i=0..3, f=4..7, g=8..11, o=12..15) ----
#pragma unroll
    for (int q = 0; q < 4; ++q) {
#pragma unroll
      for (int r = 0; r < 4; ++r) {
        float ig = sigf(acc[q][r]);
        float fg = sigf(acc[4 + q][r]);
        float gg = tanhf_(acc[8 + q][r]);
        float og = sigf(acc[12 + q][r]);
        float c = fg * c1[q][r] + ig * gg;
        c1[q][r] = c;
        float h = og * tanhf_(c);
        int row = quad * 4 + r;     // batch row in tile (C layout)
        int col = q * 16 + mrow;    // hidden unit
        hbuf[row * 64 + (((col >> 3) ^ (row & 7)) << 3) + (col & 7)] = f2bf(h);
      }
    }
    __syncthreads();
#pragma unroll
    for (int s = 0; s < 2; ++s) {
      int kg = quad + 4 * s;
      h1f[s] = *(const short8*)&hbuf[mrow * 64 + ((kg ^ (mrow & 7)) << 3)];
    }
    __syncthreads();

    // ---- layer 2: z2 = b2 + h1 @ W2 + h2 @ U2 ----
    floatx4 bcc[16];
#pragma unroll
    for (int n = 0; n < 16; ++n) bcc[n] = floatx4{bias2[n], bias2[n], bias2[n], bias2[n]};
#pragma unroll
    for (int n = 0; n < 16; ++n) {
#pragma unroll
      for (int s = 0; s < 2; ++s)
        bcc[n] = __builtin_amdgcn_mfma_f32_16x16x32_bf16(
            h1f[s], *(const short8*)(w2p + n * 1024 + s * 32), bcc[n], 0, 0, 0);
#pragma unroll
      for (int s = 0; s < 2; ++s)
        bcc[n] = __builtin_amdgcn_mfma_f32_16x16x32_bf16(
            h2f[s], *(const short8*)(u2p + n * 1024 + s * 32), bcc[n], 0, 0, 0);
    }

    // ---- layer 2 elementwise (activation = sigmoid everywhere) + output ----
    float* ot = outp + t * 64;
#pragma unroll
    for (int q = 0; q < 4; ++q) {
#pragma unroll
      for (int r = 0; r < 4; ++r) {
        float ig = sigf(bcc[q][r]);
        float fg = sigf(bcc[4 + q][r]);
        float gg = sigf(bcc[8 + q][r]);
        float og = sigf(bcc[12 + q][r]);
        float c = fg * c2[q][r] + ig * gg;
        c2[q][r] = c;
        float h = og * sigf(c);
        int row = quad * 4 + r;
        int col = q * 16 + mrow;
        hbuf[row * 64 + (((col >> 3) ^ (row & 7)) << 3) + (col & 7)] = f2bf(h);
        ot[(size_t)row * 8192 + col] = h;
      }
    }
    __syncthreads();
#pragma unroll
    for (int s = 0; s < 2; ++s) {
      int kg = quad + 4 * s;
      h2f[s] = *(const short8*)&hbuf[mrow * 64 + ((kg ^ (mrow & 7)) << 3)];
    }
    __syncthreads();
  }
}

extern "C" void kernel_launch(void* const* d_in, const int* in_sizes, int n_in,
                              void* d_out, int out_size, void* d_ws, size_t ws_size,
                              hipStream_t stream) {
  const float* x  = (const float*)d_in[0];
  const float* W1 = (const float*)d_in[1];
  const float* U1 = (const float*)d_in[2];
  const float* b1 = (const float*)d_in[3];
  const float* W2 = (const float*)d_in[4];
  const float* U2 = (const float*)d_in[5];
  const float* b2 = (const float*)d_in[6];
  float* out = (float*)d_out;

  short* w1t = (short*)d_ws;        // [256][128] bf16
  short* u1t = w1t + 32768;         // [256][64]
  short* w2t = u1t + 16384;         // [256][64]
  short* u2t = w2t + 16384;         // [256][64]

  hipLaunchKernelGGL(wtrans, dim3(256), dim3(128), 0, stream, W1, w1t, 128);
  hipLaunchKernelGGL(wtrans, dim3(256), dim3(64), 0, stream, U1, u1t, 64);
  hipLaunchKernelGGL(wtrans, dim3(256), dim3(64), 0, stream, W2, w2t, 64);
  hipLaunchKernelGGL(wtrans, dim3(256), dim3(64), 0, stream, U2, u2t, 64);
  hipLaunchKernelGGL(lstm_fused, dim3(128), dim3(64), 0, stream,
                     x, w1t, u1t, w2t, u2t, b1, b2, out);
}

// Round 2
// 412.160 us; speedup vs baseline: 5.2863x; 5.2863x over previous
//
#include <hip/hip_runtime.h>
#include <stdint.h>

typedef __attribute__((ext_vector_type(8))) short short8;
typedef __attribute__((ext_vector_type(4))) float floatx4;

#define NB 2048
#define TT 128
#define DD 128

__device__ __forceinline__ short f2bf(float f) {
  union { float f; uint32_t u; } v; v.f = f;
  uint32_t u = v.u;
  u += 0x7fffu + ((u >> 16) & 1u);   // round-to-nearest-even
  return (short)(u >> 16);
}

__device__ __forceinline__ float sigf(float x) {
  return __builtin_amdgcn_rcpf(1.f + __expf(-x));
}
__device__ __forceinline__ float tanhf_(float x) {
  return 2.f * __builtin_amdgcn_rcpf(1.f + __expf(-2.f * x)) - 1.f;
}

// src: fp32 [K][256] row-major (Keras kernel layout), dst: bf16 [256][K]
__global__ void wtrans(const float* __restrict__ src, short* __restrict__ dst, int K) {
  int n = blockIdx.x;   // 0..255 gate column
  int k = threadIdx.x;  // 0..K-1
  dst[n * K + k] = f2bf(src[k * 256 + n]);
}

// 4 waves per block, 16 batch rows per block. Wave w owns hidden cols
// 16w..16w+15 (gate tiles n = {w, 4+w, 8+w, 12+w}); ALL its weights live in
// registers (160 VGPRs) -> no weight memory traffic inside the T-loop.
// h is exchanged between waves through LDS each timestep (2 buffers, 2 barriers).
// MFMA 16x16x32 bf16 layouts (verified m89/m120):
//   A-frag: A[m = lane&15][k = (lane>>4)*8 + j]
//   B-frag: B[k = (lane>>4)*8 + j][n = lane&15]
//   C/D   : col = lane&15, row = (lane>>4)*4 + reg
__global__ __launch_bounds__(256, 1) void lstm_fused(
    const float* __restrict__ x,
    const short* __restrict__ w1t, const short* __restrict__ u1t,
    const short* __restrict__ w2t, const short* __restrict__ u2t,
    const float* __restrict__ b1, const float* __restrict__ b2,
    float* __restrict__ out) {
  __shared__ short hb1[16 * 64];  // h1 exchange, XOR-swizzled 16B groups
  __shared__ short hb2[16 * 64];  // h2 exchange

  const int tid = threadIdx.x;
  const int w = tid >> 6;        // wave id: hidden-column slice
  const int lane = tid & 63;
  const int mrow = lane & 15;
  const int quad = lane >> 4;
  const int rowbase = blockIdx.x * 16;
  const int colw = w * 16 + mrow;  // this lane's hidden column

  // ---- load this wave's weight slice into registers (once) ----
  short8 w1r[4][4], u1r[4][2], w2r[4][2], u2r[4][2];
#pragma unroll
  for (int g = 0; g < 4; ++g) {
    const int n = g * 4 + w;  // gate tile: g=0:i 1:f 2:g 3:o, cols 16w..16w+15
#pragma unroll
    for (int s = 0; s < 4; ++s)
      w1r[g][s] = *(const short8*)(w1t + n * 2048 + mrow * 128 + quad * 8 + s * 32);
#pragma unroll
    for (int s = 0; s < 2; ++s) {
      u1r[g][s] = *(const short8*)(u1t + n * 1024 + mrow * 64 + quad * 8 + s * 32);
      w2r[g][s] = *(const short8*)(w2t + n * 1024 + mrow * 64 + quad * 8 + s * 32);
      u2r[g][s] = *(const short8*)(u2t + n * 1024 + mrow * 64 + quad * 8 + s * 32);
    }
  }
  float bias1[4], bias2[4];
#pragma unroll
  for (int g = 0; g < 4; ++g) {
    bias1[g] = b1[g * 64 + colw];
    bias2[g] = b2[g * 64 + colw];
  }

  const float* xp = x + (size_t)(rowbase + mrow) * (TT * DD) + quad * 8;
  float* outp = out + (size_t)rowbase * 8192 + colw;

  short8 h1f[2], h2f[2];
  floatx4 c1, c2;
#pragma unroll
  for (int s = 0; s < 2; ++s)
#pragma unroll
    for (int j = 0; j < 8; ++j) { h1f[s][j] = 0; h2f[s][j] = 0; }
#pragma unroll
  for (int r = 0; r < 4; ++r) { c1[r] = 0.f; c2[r] = 0.f; }

  // preload x_0 (raw fp32)
  floatx4 xraw[8];
#pragma unroll
  for (int s = 0; s < 8; ++s)
    xraw[s] = *(const floatx4*)(xp + (s >> 1) * 32 + (s & 1) * 4);

#pragma unroll 1
  for (int t = 0; t < TT; ++t) {
    // convert prefetched x to bf16 A-frags
    short8 xf[4];
#pragma unroll
    for (int s = 0; s < 4; ++s) {
      short8 v;
#pragma unroll
      for (int j = 0; j < 4; ++j) {
        v[j] = f2bf(xraw[2 * s][j]);
        v[4 + j] = f2bf(xraw[2 * s + 1][j]);
      }
      xf[s] = v;
    }

    // ---- layer 1: z1 = b1 + x_t @ W1 + h1 @ U1 (all weights in regs) ----
    floatx4 acc[4];
#pragma unroll
    for (int g = 0; g < 4; ++g)
      acc[g] = floatx4{bias1[g], bias1[g], bias1[g], bias1[g]};
#pragma unroll
    for (int g = 0; g < 4; ++g) {
#pragma unroll
      for (int s = 0; s < 4; ++s)
        acc[g] = __builtin_amdgcn_mfma_f32_16x16x32_bf16(xf[s], w1r[g][s], acc[g], 0, 0, 0);
#pragma unroll
      for (int s = 0; s < 2; ++s)
        acc[g] = __builtin_amdgcn_mfma_f32_16x16x32_bf16(h1f[s], u1r[g][s], acc[g], 0, 0, 0);
    }

    // prefetch next timestep's x (hides HBM latency behind L2 compute)
    {
      const float* xt = xp + (size_t)(t + 1 < TT ? t + 1 : TT - 1) * DD;
#pragma unroll
      for (int s = 0; s < 8; ++s)
        xraw[s] = *(const floatx4*)(xt + (s >> 1) * 32 + (s & 1) * 4);
    }

    // ---- layer 1 elementwise (acc: 0=i 1=f 2=g 3=o) ----
#pragma unroll
    for (int r = 0; r < 4; ++r) {
      float ig = sigf(acc[0][r]);
      float fg = sigf(acc[1][r]);
      float gg = tanhf_(acc[2][r]);
      float og = sigf(acc[3][r]);
      float c = fg * c1[r] + ig * gg;
      c1[r] = c;
      float h = og * tanhf_(c);
      int row = quad * 4 + r;
      hb1[row * 64 + (((colw >> 3) ^ (row & 7)) << 3) + (colw & 7)] = f2bf(h);
    }
    __syncthreads();
#pragma unroll
    for (int s = 0; s < 2; ++s) {
      int kg = quad + 4 * s;
      h1f[s] = *(const short8*)&hb1[mrow * 64 + ((kg ^ (mrow & 7)) << 3)];
    }

    // ---- layer 2: z2 = b2 + h1 @ W2 + h2 @ U2 ----
    floatx4 bcc[4];
#pragma unroll
    for (int g = 0; g < 4; ++g)
      bcc[g] = floatx4{bias2[g], bias2[g], bias2[g], bias2[g]};
#pragma unroll
    for (int g = 0; g < 4; ++g) {
#pragma unroll
      for (int s = 0; s < 2; ++s)
        bcc[g] = __builtin_amdgcn_mfma_f32_16x16x32_bf16(h1f[s], w2r[g][s], bcc[g], 0, 0, 0);
#pragma unroll
      for (int s = 0; s < 2; ++s)
        bcc[g] = __builtin_amdgcn_mfma_f32_16x16x32_bf16(h2f[s], u2r[g][s], bcc[g], 0, 0, 0);
    }

    // ---- layer 2 elementwise (activation = sigmoid) + output store ----
    float* ot = outp + t * 64;
#pragma unroll
    for (int r = 0; r < 4; ++r) {
      float ig = sigf(bcc[0][r]);
      float fg = sigf(bcc[1][r]);
      float gg = sigf(bcc[2][r]);
      float og = sigf(bcc[3][r]);
      float c = fg * c2[r] + ig * gg;
      c2[r] = c;
      float h = og * sigf(c);
      int row = quad * 4 + r;
      hb2[row * 64 + (((colw >> 3) ^ (row & 7)) << 3) + (colw & 7)] = f2bf(h);
      ot[(size_t)row * 8192] = h;
    }
    __syncthreads();
#pragma unroll
    for (int s = 0; s < 2; ++s) {
      int kg = quad + 4 * s;
      h2f[s] = *(const short8*)&hb2[mrow * 64 + ((kg ^ (mrow & 7)) << 3)];
    }
  }
}

extern "C" void kernel_launch(void* const* d_in, const int* in_sizes, int n_in,
                              void* d_out, int out_size, void* d_ws, size_t ws_size,
                              hipStream_t stream) {
  const float* x  = (const float*)d_in[0];
  const float* W1 = (const float*)d_in[1];
  const float* U1 = (const float*)d_in[2];
  const float* b1 = (const float*)d_in[3];
  const float* W2 = (const float*)d_in[4];
  const float* U2 = (const float*)d_in[5];
  const float* b2 = (const float*)d_in[6];
  float* out = (float*)d_out;

  short* w1t = (short*)d_ws;        // [256][128] bf16
  short* u1t = w1t + 32768;         // [256][64]
  short* w2t = u1t + 16384;         // [256][64]
  short* u2t = w2t + 16384;         // [256][64]

  hipLaunchKernelGGL(wtrans, dim3(256), dim3(128), 0, stream, W1, w1t, 128);
  hipLaunchKernelGGL(wtrans, dim3(256), dim3(64), 0, stream, U1, u1t, 64);
  hipLaunchKernelGGL(wtrans, dim3(256), dim3(64), 0, stream, W2, w2t, 64);
  hipLaunchKernelGGL(wtrans, dim3(256), dim3(64), 0, stream, U2, u2t, 64);
  hipLaunchKernelGGL(lstm_fused, dim3(128), dim3(256), 0, stream,
                     x, w1t, u1t, w2t, u2t, b1, b2, out);
}

// Round 3
// 302.018 us; speedup vs baseline: 7.2141x; 1.3647x over previous
//
#include <hip/hip_runtime.h>
#include <stdint.h>

typedef __attribute__((ext_vector_type(8))) short short8;
typedef __attribute__((ext_vector_type(4))) short short4_t;
typedef __attribute__((ext_vector_type(4))) float floatx4;

#define TT 128
#define DD 128

__device__ __forceinline__ short f2bf(float f) {
  union { float f; uint32_t u; } v; v.f = f;
  uint32_t u = v.u;
  u += 0x7fffu + ((u >> 16) & 1u);   // round-to-nearest-even
  return (short)(u >> 16);
}

__device__ __forceinline__ float sigf(float x) {
  return __builtin_amdgcn_rcpf(1.f + __expf(-x));
}
__device__ __forceinline__ float tanhf_(float x) {
  return 2.f * __builtin_amdgcn_rcpf(1.f + __expf(-2.f * x)) - 1.f;
}

// One launch: transpose+bf16-convert all four weight matrices.
// src fp32 [K][256] (Keras layout) -> dst bf16 [256][K]
__global__ void wtrans_all(const float* __restrict__ W1, const float* __restrict__ U1,
                           const float* __restrict__ W2, const float* __restrict__ U2,
                           short* __restrict__ w1t, short* __restrict__ u1t,
                           short* __restrict__ w2t, short* __restrict__ u2t) {
  int n = blockIdx.x;   // gate column 0..255
  int k = threadIdx.x;  // 0..127
  w1t[n * 128 + k] = f2bf(W1[k * 256 + n]);
  if (k < 64) {
    u1t[n * 64 + k] = f2bf(U1[k * 256 + n]);
    w2t[n * 64 + k] = f2bf(W2[k * 256 + n]);
    u2t[n * 64 + k] = f2bf(U2[k * 256 + n]);
  }
}

// 256 blocks (1/CU) x 4 waves, 8 batch rows per block.
// Batch rows sit in M-rows {0,1,4,5,8,9,12,13} so C-layout rows quad*4+{0,1}
// are the real rows -> elementwise = 2 elems/lane across ALL 64 lanes.
// Wave w owns hidden cols 16w..16w+15; its weights live in registers.
// x(t+1) is converted fp32->bf16 cooperatively (256 threads) into swizzled LDS.
// MFMA 16x16x32 bf16 layouts (verified m89/m120):
//   A-frag: A[m = lane&15][k = (lane>>4)*8 + j] (+32/kstep)
//   B-frag: B[k = (lane>>4)*8 + j][n = lane&15]
//   C/D   : col = lane&15, row = (lane>>4)*4 + reg
__global__ __launch_bounds__(256, 1) void lstm_fused(
    const float* __restrict__ x,
    const short* __restrict__ w1t, const short* __restrict__ u1t,
    const short* __restrict__ w2t, const short* __restrict__ u2t,
    const float* __restrict__ b1, const float* __restrict__ b2,
    float* __restrict__ out) {
  __shared__ short hb1[8 * 64];    // h1 exchange (XOR-swizzled 8-elem blocks)
  __shared__ short hb2[8 * 64];    // h2 exchange
  __shared__ short xbuf[8 * 128];  // bf16 x(t+1) staging

  const int tid = threadIdx.x;
  const int w = tid >> 6;          // wave id -> hidden-col slice
  const int lane = tid & 63;
  const int mrow = lane & 15;
  const int quad = lane >> 4;
  const int rowbase = blockIdx.x * 8;
  const int colw = w * 16 + mrow;
  const int br_a = 2 * (mrow >> 2) + (mrow & 1);  // A-frag batch row (dups at mrow&2)

  // ---- weight slice -> registers ----
  short8 w1r[4][4], u1r[4][2], w2r[4][2], u2r[4][2];
#pragma unroll
  for (int g = 0; g < 4; ++g) {
    const int n = g * 4 + w;  // gate tile (g=0:i 1:f 2:g 3:o), cols 16w..16w+15
#pragma unroll
    for (int s = 0; s < 4; ++s)
      w1r[g][s] = *(const short8*)(w1t + n * 2048 + mrow * 128 + quad * 8 + s * 32);
#pragma unroll
    for (int s = 0; s < 2; ++s) {
      u1r[g][s] = *(const short8*)(u1t + n * 1024 + mrow * 64 + quad * 8 + s * 32);
      w2r[g][s] = *(const short8*)(w2t + n * 1024 + mrow * 64 + quad * 8 + s * 32);
      u2r[g][s] = *(const short8*)(u2t + n * 1024 + mrow * 64 + quad * 8 + s * 32);
    }
  }
  float bias1[4], bias2[4];
#pragma unroll
  for (int g = 0; g < 4; ++g) {
    bias1[g] = b1[g * 64 + colw];
    bias2[g] = b2[g * 64 + colw];
  }

  // ---- x staging mapping: thread -> (row, 16B d-group) ----
  const int xr = tid >> 5;    // batch row 0..7
  const int dgrp = tid & 31;  // 4-elem group within D=128
  const float* xload = x + (size_t)(rowbase + xr) * (TT * DD) + dgrp * 4;
  const int cbx = dgrp >> 1;
  const int px = (cbx & 8) | ((cbx ^ xr) & 7);
  short* xwr = &xbuf[xr * 128 + px * 8 + (dgrp & 1) * 4];

  short8 h1f[2], h2f[2];
  float c1[2] = {0.f, 0.f}, c2[2] = {0.f, 0.f};
#pragma unroll
  for (int s = 0; s < 2; ++s)
#pragma unroll
    for (int j = 0; j < 8; ++j) { h1f[s][j] = 0; h2f[s][j] = 0; }

  // ---- prologue: stage x(0), read frags, prefetch x(1) ----
  {
    floatx4 x0 = *(const floatx4*)(xload);
    short4_t v;
#pragma unroll
    for (int j = 0; j < 4; ++j) v[j] = f2bf(x0[j]);
    *(short4_t*)xwr = v;
  }
  __syncthreads();
  short8 xf[4];
#pragma unroll
  for (int s = 0; s < 4; ++s) {
    int cb = quad + 4 * s;
    int p = (cb & 8) | ((cb ^ br_a) & 7);
    xf[s] = *(const short8*)&xbuf[br_a * 128 + p * 8];
  }
  __syncthreads();
  floatx4 xraw = *(const floatx4*)(xload + DD);  // x(1)

#pragma unroll 1
  for (int t = 0; t < TT; ++t) {
    // ---- layer 1 MFMA: z1 = b1 + x_t @ W1 + h1 @ U1 ----
    floatx4 acc[4];
#pragma unroll
    for (int g = 0; g < 4; ++g)
      acc[g] = floatx4{bias1[g], bias1[g], bias1[g], bias1[g]};
#pragma unroll
    for (int g = 0; g < 4; ++g) {
#pragma unroll
      for (int s = 0; s < 4; ++s)
        acc[g] = __builtin_amdgcn_mfma_f32_16x16x32_bf16(xf[s], w1r[g][s], acc[g], 0, 0, 0);
#pragma unroll
      for (int s = 0; s < 2; ++s)
        acc[g] = __builtin_amdgcn_mfma_f32_16x16x32_bf16(h1f[s], u1r[g][s], acc[g], 0, 0, 0);
    }

    // ---- stage x(t+1) into LDS; prefetch x(t+2) ----
    {
      short4_t v;
#pragma unroll
      for (int j = 0; j < 4; ++j) v[j] = f2bf(xraw[j]);
      *(short4_t*)xwr = v;
      int tn = (t + 2 < TT) ? t + 2 : TT - 1;
      xraw = *(const floatx4*)(xload + (size_t)tn * DD);
    }

    // ---- layer 1 elementwise (2 rows/lane) ----
#pragma unroll
    for (int r = 0; r < 2; ++r) {
      float ig = sigf(acc[0][r]);
      float fg = sigf(acc[1][r]);
      float gg = tanhf_(acc[2][r]);
      float og = sigf(acc[3][r]);
      float c = fg * c1[r] + ig * gg;
      c1[r] = c;
      float h = og * tanhf_(c);
      int br = 2 * quad + r;
      int cb = colw >> 3;
      hb1[br * 64 + (((cb ^ br) & 7) << 3) + (colw & 7)] = f2bf(h);
    }
    __syncthreads();
#pragma unroll
    for (int s = 0; s < 2; ++s) {
      int kg = quad + 4 * s;
      h1f[s] = *(const short8*)&hb1[br_a * 64 + (((kg ^ br_a) & 7) << 3)];
    }
#pragma unroll
    for (int s = 0; s < 4; ++s) {
      int cb = quad + 4 * s;
      int p = (cb & 8) | ((cb ^ br_a) & 7);
      xf[s] = *(const short8*)&xbuf[br_a * 128 + p * 8];
    }

    // ---- layer 2 MFMA: z2 = b2 + h1 @ W2 + h2 @ U2 ----
    floatx4 bcc[4];
#pragma unroll
    for (int g = 0; g < 4; ++g)
      bcc[g] = floatx4{bias2[g], bias2[g], bias2[g], bias2[g]};
#pragma unroll
    for (int g = 0; g < 4; ++g) {
#pragma unroll
      for (int s = 0; s < 2; ++s)
        bcc[g] = __builtin_amdgcn_mfma_f32_16x16x32_bf16(h1f[s], w2r[g][s], bcc[g], 0, 0, 0);
#pragma unroll
      for (int s = 0; s < 2; ++s)
        bcc[g] = __builtin_amdgcn_mfma_f32_16x16x32_bf16(h2f[s], u2r[g][s], bcc[g], 0, 0, 0);
    }

    // ---- layer 2 elementwise (sigmoid activation) + output ----
#pragma unroll
    for (int r = 0; r < 2; ++r) {
      float ig = sigf(bcc[0][r]);
      float fg = sigf(bcc[1][r]);
      float gg = sigf(bcc[2][r]);
      float og = sigf(bcc[3][r]);
      float c = fg * c2[r] + ig * gg;
      c2[r] = c;
      float h = og * sigf(c);
      int br = 2 * quad + r;
      int cb = colw >> 3;
      hb2[br * 64 + (((cb ^ br) & 7) << 3) + (colw & 7)] = f2bf(h);
      out[(size_t)(rowbase + br) * 8192 + t * 64 + colw] = h;
    }
    __syncthreads();
#pragma unroll
    for (int s = 0; s < 2; ++s) {
      int kg = quad + 4 * s;
      h2f[s] = *(const short8*)&hb2[br_a * 64 + (((kg ^ br_a) & 7) << 3)];
    }
  }
}

extern "C" void kernel_launch(void* const* d_in, const int* in_sizes, int n_in,
                              void* d_out, int out_size, void* d_ws, size_t ws_size,
                              hipStream_t stream) {
  const float* x  = (const float*)d_in[0];
  const float* W1 = (const float*)d_in[1];
  const float* U1 = (const float*)d_in[2];
  const float* b1 = (const float*)d_in[3];
  const float* W2 = (const float*)d_in[4];
  const float* U2 = (const float*)d_in[5];
  const float* b2 = (const float*)d_in[6];
  float* out = (float*)d_out;

  short* w1t = (short*)d_ws;        // [256][128] bf16
  short* u1t = w1t + 32768;         // [256][64]
  short* w2t = u1t + 16384;         // [256][64]
  short* u2t = w2t + 16384;         // [256][64]

  hipLaunchKernelGGL(wtrans_all, dim3(256), dim3(128), 0, stream,
                     W1, U1, W2, U2, w1t, u1t, w2t, u2t);
  hipLaunchKernelGGL(lstm_fused, dim3(256), dim3(256), 0, stream,
                     x, w1t, u1t, w2t, u2t, b1, b2, out);
}

// Round 4
// 295.744 us; speedup vs baseline: 7.3671x; 1.0212x over previous
//
#include <hip/hip_runtime.h>
#include <stdint.h>

typedef __attribute__((ext_vector_type(8))) short short8;
typedef __attribute__((ext_vector_type(2))) short short2_t;
typedef __attribute__((ext_vector_type(4))) float floatx4;

#define TT 128
#define DD 128

__device__ __forceinline__ short f2bf(float f) {
  union { float f; uint32_t u; } v; v.f = f;
  uint32_t u = v.u;
  u += 0x7fffu + ((u >> 16) & 1u);   // round-to-nearest-even
  return (short)(u >> 16);
}

__device__ __forceinline__ float sigf(float x) {
  return __builtin_amdgcn_rcpf(1.f + __expf(-x));
}
__device__ __forceinline__ float tanhf_(float x) {
  return 2.f * __builtin_amdgcn_rcpf(1.f + __expf(-2.f * x)) - 1.f;
}

// One launch: transpose+bf16-convert all four weight matrices.
// src fp32 [K][256] (Keras layout) -> dst bf16 [256][K]
__global__ void wtrans_all(const float* __restrict__ W1, const float* __restrict__ U1,
                           const float* __restrict__ W2, const float* __restrict__ U2,
                           short* __restrict__ w1t, short* __restrict__ u1t,
                           short* __restrict__ w2t, short* __restrict__ u2t) {
  int n = blockIdx.x;   // gate column 0..255
  int k = threadIdx.x;  // 0..127
  w1t[n * 128 + k] = f2bf(W1[k * 256 + n]);
  if (k < 64) {
    u1t[n * 64 + k] = f2bf(U1[k * 256 + n]);
    w2t[n * 64 + k] = f2bf(W2[k * 256 + n]);
    u2t[n * 64 + k] = f2bf(U2[k * 256 + n]);
  }
}

// 512 blocks (2/CU for TLP) x 4 waves, 4 batch rows per block.
// Batch row r sits in M-rows 4r..4r+3 (A-frag lane mrow loads row mrow>>2),
// so C-layout row 4*quad (reg 0) is the real row -> elementwise is exactly
// 1 element/lane. Wave w owns hidden cols 16w..16w+15; weights in registers.
// __launch_bounds__(256,2) caps regs at 256/wave so 2 blocks/CU co-reside.
// LDS strides chosen so every access is <=2-way bank-shared (free, m136):
//   hb stride 80 elems (160B, /16=10==2 mod 8), xbuf stride 144 (288B, 18==2 mod 8).
// MFMA 16x16x32 bf16 layouts (verified m89/m120):
//   A-frag: A[m = lane&15][k = (lane>>4)*8 + j] (+32/kstep)
//   B-frag: B[k = (lane>>4)*8 + j][n = lane&15]
//   C/D   : col = lane&15, row = (lane>>4)*4 + reg
__global__ __launch_bounds__(256, 2) void lstm_fused(
    const float* __restrict__ x,
    const short* __restrict__ w1t, const short* __restrict__ u1t,
    const short* __restrict__ w2t, const short* __restrict__ u2t,
    const float* __restrict__ b1, const float* __restrict__ b2,
    float* __restrict__ out) {
  __shared__ short hb1[4 * 80];    // h1 exchange
  __shared__ short hb2[4 * 80];    // h2 exchange
  __shared__ short xbuf[4 * 144];  // bf16 x(t+1) staging

  const int tid = threadIdx.x;
  const int w = tid >> 6;          // wave id -> hidden-col slice
  const int lane = tid & 63;
  const int mrow = lane & 15;
  const int quad = lane >> 4;
  const int rowbase = blockIdx.x * 4;
  const int colw = w * 16 + mrow;
  const int br_a = mrow >> 2;      // A-frag batch row (4x duplicated over mrow&3)

  // ---- weight slice -> registers ----
  short8 w1r[4][4], u1r[4][2], w2r[4][2], u2r[4][2];
#pragma unroll
  for (int g = 0; g < 4; ++g) {
    const int n = g * 4 + w;  // gate tile (g=0:i 1:f 2:g 3:o), cols 16w..16w+15
#pragma unroll
    for (int s = 0; s < 4; ++s)
      w1r[g][s] = *(const short8*)(w1t + n * 2048 + mrow * 128 + quad * 8 + s * 32);
#pragma unroll
    for (int s = 0; s < 2; ++s) {
      u1r[g][s] = *(const short8*)(u1t + n * 1024 + mrow * 64 + quad * 8 + s * 32);
      w2r[g][s] = *(const short8*)(w2t + n * 1024 + mrow * 64 + quad * 8 + s * 32);
      u2r[g][s] = *(const short8*)(u2t + n * 1024 + mrow * 64 + quad * 8 + s * 32);
    }
  }
  float bias1[4], bias2[4];
#pragma unroll
  for (int g = 0; g < 4; ++g) {
    bias1[g] = b1[g * 64 + colw];
    bias2[g] = b2[g * 64 + colw];
  }

  // ---- x staging mapping: thread -> (row = tid>>6, 2 floats) ----
  const int xr = tid >> 6;
  const int xc = (tid & 63) * 2;
  const float* xload = x + (size_t)(rowbase + xr) * (TT * DD) + xc;
  short* xwr = &xbuf[xr * 144 + xc];

  short8 h1f[2], h2f[2];
  float c1 = 0.f, c2 = 0.f;
#pragma unroll
  for (int s = 0; s < 2; ++s)
#pragma unroll
    for (int j = 0; j < 8; ++j) { h1f[s][j] = 0; h2f[s][j] = 0; }

  // ---- prologue: stage x(0), read frags, prefetch x(1) ----
  {
    float a0 = xload[0], a1 = xload[1];
    *(short2_t*)xwr = short2_t{f2bf(a0), f2bf(a1)};
  }
  __syncthreads();
  short8 xf[4];
#pragma unroll
  for (int s = 0; s < 4; ++s)
    xf[s] = *(const short8*)&xbuf[br_a * 144 + (quad + 4 * s) * 8];
  __syncthreads();
  float xr0 = xload[DD], xr1 = xload[DD + 1];  // x(1)

#pragma unroll 1
  for (int t = 0; t < TT; ++t) {
    // ---- layer 1 MFMA: z1 = x_t @ W1 + h1 @ U1 (bias added later) ----
    floatx4 acc[4];
#pragma unroll
    for (int g = 0; g < 4; ++g) acc[g] = floatx4{0.f, 0.f, 0.f, 0.f};
#pragma unroll
    for (int g = 0; g < 4; ++g) {
#pragma unroll
      for (int s = 0; s < 4; ++s)
        acc[g] = __builtin_amdgcn_mfma_f32_16x16x32_bf16(xf[s], w1r[g][s], acc[g], 0, 0, 0);
#pragma unroll
      for (int s = 0; s < 2; ++s)
        acc[g] = __builtin_amdgcn_mfma_f32_16x16x32_bf16(h1f[s], u1r[g][s], acc[g], 0, 0, 0);
    }

    // ---- stage x(t+1) into LDS; prefetch x(t+2) ----
    *(short2_t*)xwr = short2_t{f2bf(xr0), f2bf(xr1)};
    {
      int tn = (t + 2 < TT) ? t + 2 : TT - 1;
      xr0 = xload[(size_t)tn * DD];
      xr1 = xload[(size_t)tn * DD + 1];
    }

    // ---- layer 1 elementwise (1 elem/lane: batch row = quad, col = colw) ----
    {
      float ig = sigf(acc[0][0] + bias1[0]);
      float fg = sigf(acc[1][0] + bias1[1]);
      float gg = tanhf_(acc[2][0] + bias1[2]);
      float og = sigf(acc[3][0] + bias1[3]);
      float c = fg * c1 + ig * gg;
      c1 = c;
      float h = og * tanhf_(c);
      hb1[quad * 80 + colw] = f2bf(h);
    }
    __syncthreads();
#pragma unroll
    for (int s = 0; s < 2; ++s)
      h1f[s] = *(const short8*)&hb1[br_a * 80 + (quad + 4 * s) * 8];
#pragma unroll
    for (int s = 0; s < 4; ++s)
      xf[s] = *(const short8*)&xbuf[br_a * 144 + (quad + 4 * s) * 8];

    // ---- layer 2 MFMA: z2 = h1 @ W2 + h2 @ U2 ----
    floatx4 bcc[4];
#pragma unroll
    for (int g = 0; g < 4; ++g) bcc[g] = floatx4{0.f, 0.f, 0.f, 0.f};
#pragma unroll
    for (int g = 0; g < 4; ++g) {
#pragma unroll
      for (int s = 0; s < 2; ++s)
        bcc[g] = __builtin_amdgcn_mfma_f32_16x16x32_bf16(h1f[s], w2r[g][s], bcc[g], 0, 0, 0);
#pragma unroll
      for (int s = 0; s < 2; ++s)
        bcc[g] = __builtin_amdgcn_mfma_f32_16x16x32_bf16(h2f[s], u2r[g][s], bcc[g], 0, 0, 0);
    }

    // ---- layer 2 elementwise (sigmoid activation) + output ----
    {
      float ig = sigf(bcc[0][0] + bias2[0]);
      float fg = sigf(bcc[1][0] + bias2[1]);
      float gg = sigf(bcc[2][0] + bias2[2]);
      float og = sigf(bcc[3][0] + bias2[3]);
      float c = fg * c2 + ig * gg;
      c2 = c;
      float h = og * sigf(c);
      hb2[quad * 80 + colw] = f2bf(h);
      out[(size_t)(rowbase + quad) * 8192 + t * 64 + colw] = h;
    }
    __syncthreads();
#pragma unroll
    for (int s = 0; s < 2; ++s)
      h2f[s] = *(const short8*)&hb2[br_a * 80 + (quad + 4 * s) * 8];
  }
}

extern "C" void kernel_launch(void* const* d_in, const int* in_sizes, int n_in,
                              void* d_out, int out_size, void* d_ws, size_t ws_size,
                              hipStream_t stream) {
  const float* x  = (const float*)d_in[0];
  const float* W1 = (const float*)d_in[1];
  const float* U1 = (const float*)d_in[2];
  const float* b1 = (const float*)d_in[3];
  const float* W2 = (const float*)d_in[4];
  const float* U2 = (const float*)d_in[5];
  const float* b2 = (const float*)d_in[6];
  float* out = (float*)d_out;

  short* w1t = (short*)d_ws;        // [256][128] bf16
  short* u1t = w1t + 32768;         // [256][64]
  short* w2t = u1t + 16384;         // [256][64]
  short* u2t = w2t + 16384;         // [256][64]

  hipLaunchKernelGGL(wtrans_all, dim3(256), dim3(128), 0, stream,
                     W1, U1, W2, U2, w1t, u1t, w2t, u2t);
  hipLaunchKernelGGL(lstm_fused, dim3(512), dim3(256), 0, stream,
                     x, w1t, u1t, w2t, u2t, b1, b2, out);
}